// Round 3
// baseline (253.922 us; speedup 1.0000x reference)
//
#include <hip/hip_runtime.h>

#define TT 512

// ---- DPP cross-lane helpers (VALU pipe; rows of 16 lanes) ----
__device__ __forceinline__ int rori_(int v) {           // row_ror:1
    return __builtin_amdgcn_update_dpp(0, v, 0x121, 0xf, 0xf, true);
}
__device__ __forceinline__ float rorf_(float v) {
    return __int_as_float(rori_(__float_as_int(v)));
}
template <int CTRL>
__device__ __forceinline__ float shrf_(float v) {       // row_shr:N, invalid lanes -> 0
    return __int_as_float(__builtin_amdgcn_update_dpp(0, __float_as_int(v), CTRL, 0xf, 0xf, true));
}
__device__ __forceinline__ float sigmoidf_(float v) {
    return __builtin_amdgcn_rcpf(1.f + __expf(-v));
}

__launch_bounds__(64, 1)
__global__ void gru_dpp(const float* __restrict__ x,
                        const float* __restrict__ W1, const float* __restrict__ Ur1,
                        const float* __restrict__ b1,
                        const float* __restrict__ W2, const float* __restrict__ Ur2,
                        const float* __restrict__ b2,
                        const float* __restrict__ Wd, const float* __restrict__ bd,
                        const float* __restrict__ Wo, const float* __restrict__ bo,
                        float* __restrict__ out)
{
    const int lane = threadIdx.x & 63;
    const int g    = lane >> 4;        // row group within wave (DPP row = 16 lanes)
    const int j    = lane & 15;        // GRU2 / dense unit owned by this lane
    const int u1   = j & 7;            // GRU1 unit (duplicated across j and j+8)
    const int row  = blockIdx.x * 4 + g;
    const float* xrow = x + (size_t)row * TT * 8;

    // ---- trace the actual DPP ror1 permutation (direction-proof weight order) ----
    int Lk[16];
    {
        int L = j;
        Lk[0] = j;
#pragma unroll
        for (int k = 1; k < 16; ++k) { L = rori_(L); Lk[k] = L; }
    }

    // ---- weights into registers ----
    float w1z[8], w1r[8], w1h[8];                     // x-side GRU1 (own column)
#pragma unroll
    for (int f = 0; f < 8; ++f) {
        w1z[f] = W1[f * 24 + u1];
        w1r[f] = W1[f * 24 + 8 + u1];
        w1h[f] = W1[f * 24 + 16 + u1];
    }
    float q1z[8], q1r[8], q1h[8], w2z[8], w2r[8], w2h[8];  // rotation-ordered
#pragma unroll
    for (int k = 0; k < 8; ++k) {
        const int s1 = Lk[k] & 7;
        q1z[k] = Ur1[s1 * 24 + u1];
        q1r[k] = Ur1[s1 * 24 + 8 + u1];
        q1h[k] = Ur1[s1 * 24 + 16 + u1];
        w2z[k] = W2[s1 * 48 + j];
        w2r[k] = W2[s1 * 48 + 16 + j];
        w2h[k] = W2[s1 * 48 + 32 + j];
    }
    float q2z[16], q2r[16], q2h[16], wdk[16];              // rotation-ordered
#pragma unroll
    for (int k = 0; k < 16; ++k) {
        const int s2 = Lk[k];
        q2z[k] = Ur2[s2 * 48 + j];
        q2r[k] = Ur2[s2 * 48 + 16 + j];
        q2h[k] = Ur2[s2 * 48 + 32 + j];
        wdk[k] = Wd[s2 * 16 + j];
    }
    const float bz1 = b1[u1],      br1 = b1[8 + u1],  bh1 = b1[16 + u1];
    const float cz1 = b1[24 + u1], cr1 = b1[32 + u1], ch1 = b1[40 + u1];
    const float bz2 = b2[j],       br2 = b2[16 + j],  bh2 = b2[32 + j];
    const float cz2 = b2[48 + j],  cr2 = b2[64 + j],  ch2 = b2[80 + j];
    const float bdj = bd[j], woj = Wo[j], boo = bo[0];

    float h1own = 0.f, h2own = 0.f;

    // ---- x register queue, 3 steps ahead (static indices via 4x unroll) ----
    float4 xq[4][2];
#pragma unroll
    for (int k = 0; k < 3; ++k) {
        const float4* xp = (const float4*)(xrow + k * 8);
        xq[k][0] = xp[0]; xq[k][1] = xp[1];
    }

    for (int s0 = 0; s0 < TT; s0 += 4) {
#pragma unroll
        for (int uu = 0; uu < 4; ++uu) {
            const int s = s0 + uu;

            // ---- phase A: rotate h2(s-1) [gates + dense(s-1)] and h1(s-1) ----
            float rh2 = h2own, rh1 = h1own;
            float iz2 = cz2, ir2 = cr2, ih2 = ch2, dacc = bdj;
            float iz1 = cz1, ir1 = cr1, ih1 = ch1;
            iz2  = fmaf(rh2, q2z[0], iz2);
            ir2  = fmaf(rh2, q2r[0], ir2);
            ih2  = fmaf(rh2, q2h[0], ih2);
            dacc = fmaf(rh2, wdk[0], dacc);
            iz1  = fmaf(rh1, q1z[0], iz1);
            ir1  = fmaf(rh1, q1r[0], ir1);
            ih1  = fmaf(rh1, q1h[0], ih1);
#pragma unroll
            for (int k = 1; k < 16; ++k) {
                rh2  = rorf_(rh2);
                iz2  = fmaf(rh2, q2z[k], iz2);
                ir2  = fmaf(rh2, q2r[k], ir2);
                ih2  = fmaf(rh2, q2h[k], ih2);
                dacc = fmaf(rh2, wdk[k], dacc);
                if (k < 8) {
                    rh1 = rorf_(rh1);
                    iz1 = fmaf(rh1, q1z[k], iz1);
                    ir1 = fmaf(rh1, q1r[k], ir1);
                    ih1 = fmaf(rh1, q1h[k], ih1);
                }
            }

            // ---- x-side GRU1 gates for step s ----
            const float4 a = xq[uu][0], b4 = xq[uu][1];
            const float xv[8] = {a.x, a.y, a.z, a.w, b4.x, b4.y, b4.z, b4.w};
            float gz = bz1, gr = br1, gh = bh1;
#pragma unroll
            for (int f = 0; f < 8; ++f) {
                gz = fmaf(xv[f], w1z[f], gz);
                gr = fmaf(xv[f], w1r[f], gr);
                gh = fmaf(xv[f], w1h[f], gh);
            }
            // prefetch x for step s+3 (wrap keeps it in-row; dead values at tail)
            {
                const int tf = (s + 3) & (TT - 1);
                const float4* xp = (const float4*)(xrow + tf * 8);
                xq[(uu + 3) & 3][0] = xp[0];
                xq[(uu + 3) & 3][1] = xp[1];
            }

            // ---- GRU1 nonlinearity + state ----
            const float z1  = sigmoidf_(gz + iz1);
            const float r1  = sigmoidf_(gr + ir1);
            const float hh1 = fmaxf(fmaf(r1, ih1, gh), 0.f);
            h1own = z1 * h1own + (1.f - z1) * hh1;

            // ---- W2 · h1(s): rotate new h1 ----
            float rn1 = h1own;
            float g2z = bz2, g2r = br2, g2h = bh2;
            g2z = fmaf(rn1, w2z[0], g2z);
            g2r = fmaf(rn1, w2r[0], g2r);
            g2h = fmaf(rn1, w2h[0], g2h);
#pragma unroll
            for (int k = 1; k < 8; ++k) {
                rn1 = rorf_(rn1);
                g2z = fmaf(rn1, w2z[k], g2z);
                g2r = fmaf(rn1, w2r[k], g2r);
                g2h = fmaf(rn1, w2h[k], g2h);
            }

            // ---- GRU2 nonlinearity + state ----
            const float z2  = sigmoidf_(g2z + iz2);
            const float r2  = sigmoidf_(g2r + ir2);
            const float hh2 = fmaxf(fmaf(r2, ih2, g2h), 0.f);
            h2own = z2 * h2own + (1.f - z2) * hh2;

            // ---- dense tail for step s-1 (off recurrence path) ----
            float e = fmaxf(dacc, 0.f) * woj;
            e += shrf_<0x118>(e);   // row_shr:8
            e += shrf_<0x114>(e);   // row_shr:4
            e += shrf_<0x112>(e);   // row_shr:2
            e += shrf_<0x111>(e);   // row_shr:1  -> lane 15 holds the full sum
            if (s > 0) {
                if (j == 15) out[(size_t)row * TT + (s - 1)] = e + boo;
            }
        }
    }

    // ---- epilogue: dense for s = 511 ----
    {
        float rh2  = h2own;
        float dacc = fmaf(rh2, wdk[0], bdj);
#pragma unroll
        for (int k = 1; k < 16; ++k) {
            rh2  = rorf_(rh2);
            dacc = fmaf(rh2, wdk[k], dacc);
        }
        float e = fmaxf(dacc, 0.f) * woj;
        e += shrf_<0x118>(e);
        e += shrf_<0x114>(e);
        e += shrf_<0x112>(e);
        e += shrf_<0x111>(e);
        if (j == 15) out[(size_t)row * TT + (TT - 1)] = e + boo;
    }
}

extern "C" void kernel_launch(void* const* d_in, const int* in_sizes, int n_in,
                              void* d_out, int out_size, void* d_ws, size_t ws_size,
                              hipStream_t stream) {
    const float* x   = (const float*)d_in[0];
    const float* W1  = (const float*)d_in[1];
    const float* Ur1 = (const float*)d_in[2];
    const float* b1  = (const float*)d_in[3];
    const float* W2  = (const float*)d_in[4];
    const float* Ur2 = (const float*)d_in[5];
    const float* b2  = (const float*)d_in[6];
    const float* Wd  = (const float*)d_in[7];
    const float* bd  = (const float*)d_in[8];
    const float* Wo  = (const float*)d_in[9];
    const float* bo  = (const float*)d_in[10];
    float* out = (float*)d_out;

    dim3 grid(4096 / 4);   // 1024 blocks x 1 wave = 1024 waves = 1/SIMD
    dim3 block(64);        // 1 wave: 4 rows x 16 lanes, zero LDS, zero syncthreads
    gru_dpp<<<grid, block, 0, stream>>>(x, W1, Ur1, b1, W2, Ur2, b2,
                                        Wd, bd, Wo, bo, out);
}

// Round 4
// 236.947 us; speedup vs baseline: 1.0716x; 1.0716x over previous
//
#include <hip/hip_runtime.h>

#define TT 512

// ---- DPP cross-lane helpers (VALU pipe; rows of 16 lanes) ----
__device__ __forceinline__ int rori_(int v) {           // row_ror:1 (old=src: no zero-mov)
    return __builtin_amdgcn_update_dpp(v, v, 0x121, 0xf, 0xf, true);
}
__device__ __forceinline__ float rorf_(float v) {
    return __int_as_float(rori_(__float_as_int(v)));
}
template <int CTRL>
__device__ __forceinline__ float shrf_(float v) {       // row_shr:N, invalid lanes -> 0
    return __int_as_float(__builtin_amdgcn_update_dpp(0, __float_as_int(v), CTRL, 0xf, 0xf, true));
}
__device__ __forceinline__ float sigmoidf_(float v) {
    return __builtin_amdgcn_rcpf(1.f + __expf(-v));
}

__launch_bounds__(64)
__attribute__((amdgpu_waves_per_eu(1, 1)))   // force full VGPR budget: no spills
__global__ void gru_dpp2(const float* __restrict__ x,
                         const float* __restrict__ W1, const float* __restrict__ Ur1,
                         const float* __restrict__ b1,
                         const float* __restrict__ W2, const float* __restrict__ Ur2,
                         const float* __restrict__ b2,
                         const float* __restrict__ Wd, const float* __restrict__ bd,
                         const float* __restrict__ Wo, const float* __restrict__ bo,
                         float* __restrict__ out)
{
    const int lane = threadIdx.x & 63;
    const int g    = lane >> 4;        // row group within wave (DPP row = 16 lanes)
    const int j    = lane & 15;        // GRU2 / dense unit owned by this lane
    const int u1   = j & 7;            // GRU1 unit (duplicated across j and j+8)
    const int row  = blockIdx.x * 4 + g;
    const float* xrow = x + (size_t)row * TT * 8;
    const int xoff = j & 7;            // this lane's x element within a timestep

    // ---- trace the actual DPP ror1 permutation (layout-proof weight order) ----
    int Lk[16];
    {
        int L = j;
        Lk[0] = j;
#pragma unroll
        for (int k = 1; k < 16; ++k) { L = rori_(L); Lk[k] = L; }
    }

    // ---- weights into registers (rotation-ordered where consumed rotated) ----
    float w1z[8], w1r[8], w1h[8];                 // x-side GRU1, ROTATION order
    float q1z[8], q1r[8], q1h[8], w2z[8], w2r[8], w2h[8];
#pragma unroll
    for (int k = 0; k < 8; ++k) {
        const int s1 = Lk[k] & 7;
        w1z[k] = W1[s1 * 24 + u1];
        w1r[k] = W1[s1 * 24 + 8 + u1];
        w1h[k] = W1[s1 * 24 + 16 + u1];
        q1z[k] = Ur1[s1 * 24 + u1];
        q1r[k] = Ur1[s1 * 24 + 8 + u1];
        q1h[k] = Ur1[s1 * 24 + 16 + u1];
        w2z[k] = W2[s1 * 48 + j];
        w2r[k] = W2[s1 * 48 + 16 + j];
        w2h[k] = W2[s1 * 48 + 32 + j];
    }
    float q2z[16], q2r[16], q2h[16], wdk[16];
#pragma unroll
    for (int k = 0; k < 16; ++k) {
        const int s2 = Lk[k];
        q2z[k] = Ur2[s2 * 48 + j];
        q2r[k] = Ur2[s2 * 48 + 16 + j];
        q2h[k] = Ur2[s2 * 48 + 32 + j];
        wdk[k] = Wd[s2 * 16 + j];
    }
    // biases: z/r input+recurrent pairs merged (saves regs + adds)
    const float bzc1 = b1[u1] + b1[24 + u1];
    const float brc1 = b1[8 + u1] + b1[32 + u1];
    const float bh1  = b1[16 + u1], ch1 = b1[40 + u1];
    const float bzc2 = b2[j] + b2[48 + j];
    const float brc2 = b2[16 + j] + b2[64 + j];
    const float bh2  = b2[32 + j], ch2 = b2[80 + j];
    const float bdj  = bd[j], woj = Wo[j], boo = bo[0];

    float h1own = 0.f, h2own = 0.f;

    // ---- x queue: ONE float per lane per step, 3 steps ahead ----
    float xq[4];
#pragma unroll
    for (int k = 0; k < 3; ++k) xq[k] = xrow[k * 8 + xoff];

    for (int s0 = 0; s0 < TT; s0 += 4) {
#pragma unroll
        for (int uu = 0; uu < 4; ++uu) {
            const int s = s0 + uu;

            // ---- phase A: three interleaved rotation chains ----
            float rh2 = h2own, rh1 = h1own, rx = xq[uu];
            float iz2 = bzc2, ir2 = brc2, ih2 = ch2, dacc = bdj;
            float iz1 = 0.f,  ir1 = 0.f,  ih1 = ch1;
            float gz  = bzc1, gr  = brc1, gh  = bh1;
            iz2  = fmaf(rh2, q2z[0], iz2);
            ir2  = fmaf(rh2, q2r[0], ir2);
            ih2  = fmaf(rh2, q2h[0], ih2);
            dacc = fmaf(rh2, wdk[0], dacc);
            iz1  = fmaf(rh1, q1z[0], iz1);
            ir1  = fmaf(rh1, q1r[0], ir1);
            ih1  = fmaf(rh1, q1h[0], ih1);
            gz   = fmaf(rx,  w1z[0], gz);
            gr   = fmaf(rx,  w1r[0], gr);
            gh   = fmaf(rx,  w1h[0], gh);
#pragma unroll
            for (int k = 1; k < 16; ++k) {
                rh2  = rorf_(rh2);
                iz2  = fmaf(rh2, q2z[k], iz2);
                ir2  = fmaf(rh2, q2r[k], ir2);
                ih2  = fmaf(rh2, q2h[k], ih2);
                dacc = fmaf(rh2, wdk[k], dacc);
                if (k < 8) {
                    rh1 = rorf_(rh1);
                    iz1 = fmaf(rh1, q1z[k], iz1);
                    ir1 = fmaf(rh1, q1r[k], ir1);
                    ih1 = fmaf(rh1, q1h[k], ih1);
                    rx  = rorf_(rx);
                    gz  = fmaf(rx, w1z[k], gz);
                    gr  = fmaf(rx, w1r[k], gr);
                    gh  = fmaf(rx, w1h[k], gh);
                }
            }

            // prefetch x for step s+3 (wrap keeps address in-row; dead at tail)
            xq[(uu + 3) & 3] = xrow[((s + 3) & (TT - 1)) * 8 + xoff];

            // ---- GRU1 nonlinearity + state ----
            const float z1  = sigmoidf_(gz + iz1);
            const float r1  = sigmoidf_(gr + ir1);
            const float hh1 = fmaxf(fmaf(r1, ih1, gh), 0.f);
            h1own = z1 * h1own + (1.f - z1) * hh1;

            // ---- W2 · h1(s): rotate new h1 ----
            float rn1 = h1own;
            float g2z = 0.f, g2r = 0.f, g2h = bh2;
            g2z = fmaf(rn1, w2z[0], g2z);
            g2r = fmaf(rn1, w2r[0], g2r);
            g2h = fmaf(rn1, w2h[0], g2h);
#pragma unroll
            for (int k = 1; k < 8; ++k) {
                rn1 = rorf_(rn1);
                g2z = fmaf(rn1, w2z[k], g2z);
                g2r = fmaf(rn1, w2r[k], g2r);
                g2h = fmaf(rn1, w2h[k], g2h);
            }

            // ---- GRU2 nonlinearity + state ----
            const float z2  = sigmoidf_(g2z + iz2);
            const float r2  = sigmoidf_(g2r + ir2);
            const float hh2 = fmaxf(fmaf(r2, ih2, g2h), 0.f);
            h2own = z2 * h2own + (1.f - z2) * hh2;

            // ---- dense tail for step s-1 (off recurrence path) ----
            float e = fmaxf(dacc, 0.f) * woj;
            e += shrf_<0x118>(e);   // row_shr:8
            e += shrf_<0x114>(e);   // row_shr:4
            e += shrf_<0x112>(e);   // row_shr:2
            e += shrf_<0x111>(e);   // row_shr:1  -> lane 15 holds the full sum
            if (s > 0) {
                if (j == 15) out[(size_t)row * TT + (s - 1)] = e + boo;
            }
        }
    }

    // ---- epilogue: dense for s = 511 ----
    {
        float rh2  = h2own;
        float dacc = fmaf(rh2, wdk[0], bdj);
#pragma unroll
        for (int k = 1; k < 16; ++k) {
            rh2  = rorf_(rh2);
            dacc = fmaf(rh2, wdk[k], dacc);
        }
        float e = fmaxf(dacc, 0.f) * woj;
        e += shrf_<0x118>(e);
        e += shrf_<0x114>(e);
        e += shrf_<0x112>(e);
        e += shrf_<0x111>(e);
        if (j == 15) out[(size_t)row * TT + (TT - 1)] = e + boo;
    }
}

extern "C" void kernel_launch(void* const* d_in, const int* in_sizes, int n_in,
                              void* d_out, int out_size, void* d_ws, size_t ws_size,
                              hipStream_t stream) {
    const float* x   = (const float*)d_in[0];
    const float* W1  = (const float*)d_in[1];
    const float* Ur1 = (const float*)d_in[2];
    const float* b1  = (const float*)d_in[3];
    const float* W2  = (const float*)d_in[4];
    const float* Ur2 = (const float*)d_in[5];
    const float* b2  = (const float*)d_in[6];
    const float* Wd  = (const float*)d_in[7];
    const float* bd  = (const float*)d_in[8];
    const float* Wo  = (const float*)d_in[9];
    const float* bo  = (const float*)d_in[10];
    float* out = (float*)d_out;

    dim3 grid(4096 / 4);   // 1024 waves = 1/SIMD (structural)
    dim3 block(64);        // 1 wave: 4 rows x 16 lanes, zero LDS
    gru_dpp2<<<grid, block, 0, stream>>>(x, W1, Ur1, b1, W2, Ur2, b2,
                                         Wd, bd, Wo, bo, out);
}

// Round 6
// 212.352 us; speedup vs baseline: 1.1958x; 1.1158x over previous
//
#include <hip/hip_runtime.h>

#define TT 512
#define LOG2E 1.44269504088896340736f

// ---- DPP helpers (rows of 16 lanes) ----
__device__ __forceinline__ int rori_(int v) {            // row_ror:1, in-place tie
    return __builtin_amdgcn_update_dpp(v, v, 0x121, 0xf, 0xf, true);
}
__device__ __forceinline__ float rorf_(float v) { return __int_as_float(rori_(__float_as_int(v))); }
__device__ __forceinline__ float ror8f_(float v) {       // row_ror:8 (pair swap)
    int i = __float_as_int(v);
    return __int_as_float(__builtin_amdgcn_update_dpp(i, i, 0x128, 0xf, 0xf, true));
}
template <int C>
__device__ __forceinline__ float shrf_(float v) {        // row_shr:N, shifted-in -> 0
    return __int_as_float(__builtin_amdgcn_update_dpp(0, __float_as_int(v), C, 0xf, 0xf, true));
}
__device__ __forceinline__ float sgm_(float v) {         // sigmoid, arg pre-scaled by log2e
    return __builtin_amdgcn_rcpf(1.f + __builtin_amdgcn_exp2f(-v));
}

__launch_bounds__(64)
__attribute__((amdgpu_waves_per_eu(1, 1)))
__global__ void gru_dpp3(const float* __restrict__ x,
                         const float* __restrict__ W1, const float* __restrict__ Ur1,
                         const float* __restrict__ b1,
                         const float* __restrict__ W2, const float* __restrict__ Ur2,
                         const float* __restrict__ b2,
                         const float* __restrict__ Wd, const float* __restrict__ bd,
                         const float* __restrict__ Wo, const float* __restrict__ bo,
                         float* __restrict__ out)
{
    const int lane = threadIdx.x & 63;
    const int g    = lane >> 4;         // 16-lane row group -> batch row
    const int j    = lane & 15;         // GRU2 / dense unit
    const int u1   = j & 7;             // GRU1 unit (pair-duplicated)
    const int hi   = j >> 3;            // 0: z-side, 1: r-side of the GRU1 pair
    const int gcol = u1 + 8 * hi;       // z column (0..7) or r column (8..15)
    const int row  = blockIdx.x * 4 + g;
    const bool ishi = (hi != 0);
    const bool isw  = (j == 15);

    // uniform base (SGPR) + per-lane-constant offset (VGPR): zero addr VALU per step
    const float* xbase = x + (size_t)blockIdx.x * 4 * TT * 8;
    const int    xoff  = g * TT * 8 + u1;
    float* outrow = out + (size_t)row * TT;

    // ---- trace the actual DPP ror1 permutation ----
    int Lk[16];
    {
        int L = j;
        Lk[0] = j;
#pragma unroll
        for (int k = 1; k < 16; ++k) { L = rori_(L); Lk[k] = L; }
    }

    // ---- weights (rotation-ordered; z/r pre-scaled by log2e) ----
    float q2z[16], q2r[16], q2h[16], wdk[16];      // rh2 ring (16 taps)
#pragma unroll
    for (int k = 0; k < 16; ++k) {
        const int s2 = Lk[k];
        q2z[k] = LOG2E * Ur2[s2 * 48 + j];
        q2r[k] = LOG2E * Ur2[s2 * 48 + 16 + j];
        q2h[k] = Ur2[s2 * 48 + 32 + j];
        wdk[k] = Wd[s2 * 16 + j];
    }
    float p2z[8], p2r[8], p2h[8], Ch[8], Qh[8];    // rn1 ring (8 taps, dual purpose)
    float Ax[8], Wx[8];                            // rx ring (8 taps)
#pragma unroll
    for (int k = 0; k < 8; ++k) {
        const int s1 = Lk[k] & 7;
        p2z[k] = LOG2E * W2[s1 * 48 + j];
        p2r[k] = LOG2E * W2[s1 * 48 + 16 + j];
        p2h[k] = W2[s1 * 48 + 32 + j];
        Ch[k]  = LOG2E * Ur1[s1 * 24 + gcol];      // next-step GRU1 z|r h-taps
        Qh[k]  = Ur1[s1 * 24 + 16 + u1];           // next-step GRU1 cand h-taps
        Ax[k]  = LOG2E * W1[s1 * 24 + gcol];       // GRU1 z|r x-taps
        Wx[k]  = W1[s1 * 24 + 16 + u1];            // GRU1 cand x-taps
    }
    const float bAzr = LOG2E * (b1[gcol] + b1[24 + gcol]);   // merged z|r bias
    const float bGh  = b1[16 + u1];                          // cand x-side bias
    const float bIh  = b1[40 + u1];                          // cand h-side bias
    const float bA2  = LOG2E * (b2[j] + b2[48 + j]);
    const float bB2  = LOG2E * (b2[16 + j] + b2[64 + j]);
    const float bC2  = b2[80 + j];
    const float bD2  = b2[32 + j];
    const float bdj  = bd[j], woj = Wo[j], boo = bo[0];

    float h1own = 0.f, h2own = 0.f;
    float azrP = bAzr, ihP = bIh;                  // carried GRU1 partials (h1(-1)=0)

    // x slots: 3 steps ahead, explicit names (no indexed arrays)
    float xA = xbase[0 * 8 + xoff];
    float xB = xbase[1 * 8 + xoff];
    float xC = xbase[2 * 8 + xoff];

#define GSTEP(SS, XCUR, XFILL)                                                  \
    {                                                                           \
        const int s = (SS);                                                     \
        /* phase A: rh2 ring (16 taps) + rx ring (8 taps) */                    \
        float rh2 = h2own, rx = XCUR;                                           \
        float za = bA2, ra = bB2, ha = bC2, da = bdj;                           \
        float azr = azrP, ghx = bGh;                                            \
        za  = fmaf(rh2, q2z[0], za);  ra = fmaf(rh2, q2r[0], ra);               \
        ha  = fmaf(rh2, q2h[0], ha);  da = fmaf(rh2, wdk[0], da);               \
        azr = fmaf(rx, Ax[0], azr);   ghx = fmaf(rx, Wx[0], ghx);               \
        _Pragma("unroll")                                                       \
        for (int k = 1; k < 16; ++k) {                                          \
            rh2 = rorf_(rh2);                                                   \
            za = fmaf(rh2, q2z[k], za);  ra = fmaf(rh2, q2r[k], ra);            \
            ha = fmaf(rh2, q2h[k], ha);  da = fmaf(rh2, wdk[k], da);            \
            if (k < 8) {                                                        \
                rx = rorf_(rx);                                                 \
                azr = fmaf(rx, Ax[k], azr);  ghx = fmaf(rx, Wx[k], ghx);        \
            }                                                                   \
        }                                                                       \
        XFILL = xbase[((s + 3) & (TT - 1)) * 8 + xoff];  /* prefetch s+3 */     \
        /* GRU1: pair swap gives both z and r pre-activations */                \
        const float swp = ror8f_(azr);                                          \
        const float s_own = sgm_(azr), s_sw = sgm_(swp);                        \
        const float z1 = ishi ? s_sw : s_own;                                   \
        const float r1 = ishi ? s_own : s_sw;                                   \
        const float hh1 = fmaxf(fmaf(r1, ihP, ghx), 0.f);                       \
        h1own = z1 * h1own + (1.f - z1) * hh1;                                  \
        /* rn1 ring: W2 taps into GRU2 accs + next-step GRU1 h-taps */          \
        float rn1 = h1own, hb = bD2;                                            \
        float azrN = bAzr, ihN = bIh;                                           \
        za   = fmaf(rn1, p2z[0], za);  ra  = fmaf(rn1, p2r[0], ra);             \
        hb   = fmaf(rn1, p2h[0], hb);                                           \
        azrN = fmaf(rn1, Ch[0], azrN); ihN = fmaf(rn1, Qh[0], ihN);             \
        _Pragma("unroll")                                                       \
        for (int k = 1; k < 8; ++k) {                                           \
            rn1  = rorf_(rn1);                                                  \
            za   = fmaf(rn1, p2z[k], za);  ra  = fmaf(rn1, p2r[k], ra);         \
            hb   = fmaf(rn1, p2h[k], hb);                                       \
            azrN = fmaf(rn1, Ch[k], azrN); ihN = fmaf(rn1, Qh[k], ihN);         \
        }                                                                       \
        azrP = azrN; ihP = ihN;                                                 \
        /* GRU2 nonlinearity + state */                                         \
        const float z2 = sgm_(za), r2 = sgm_(ra);                               \
        const float hh2 = fmaxf(fmaf(r2, ha, hb), 0.f);                         \
        h2own = z2 * h2own + (1.f - z2) * hh2;                                  \
        /* dense for step s-1 (da used h2(s-1)) */                              \
        float e = fmaxf(da, 0.f) * woj;                                         \
        e += shrf_<0x118>(e);                                                   \
        e += shrf_<0x114>(e);                                                   \
        e += shrf_<0x112>(e);                                                   \
        e += shrf_<0x111>(e);                                                   \
        if (s > 0) { if (isw) outrow[s - 1] = e + boo; }                        \
    }

    for (int s0 = 0; s0 < TT; s0 += 4) {
        GSTEP(s0 + 0, xA, xA)
        GSTEP(s0 + 1, xB, xB)
        GSTEP(s0 + 2, xC, xC)
        GSTEP(s0 + 3, xA, xA)
        // rotate slots: after 4 steps, slots hold (s0+4..s0+6) in order B,C,A
        { float t = xB; xB = xC; xC = xA; xA = t; }
    }
#undef GSTEP

    // epilogue: dense for s = 511 from final h2
    {
        float rh2 = h2own;
        float da  = fmaf(rh2, wdk[0], bdj);
#pragma unroll
        for (int k = 1; k < 16; ++k) {
            rh2 = rorf_(rh2);
            da  = fmaf(rh2, wdk[k], da);
        }
        float e = fmaxf(da, 0.f) * woj;
        e += shrf_<0x118>(e);
        e += shrf_<0x114>(e);
        e += shrf_<0x112>(e);
        e += shrf_<0x111>(e);
        if (isw) outrow[TT - 1] = e + boo;
    }
}

extern "C" void kernel_launch(void* const* d_in, const int* in_sizes, int n_in,
                              void* d_out, int out_size, void* d_ws, size_t ws_size,
                              hipStream_t stream) {
    const float* x   = (const float*)d_in[0];
    const float* W1  = (const float*)d_in[1];
    const float* Ur1 = (const float*)d_in[2];
    const float* b1  = (const float*)d_in[3];
    const float* W2  = (const float*)d_in[4];
    const float* Ur2 = (const float*)d_in[5];
    const float* b2  = (const float*)d_in[6];
    const float* Wd  = (const float*)d_in[7];
    const float* bd  = (const float*)d_in[8];
    const float* Wo  = (const float*)d_in[9];
    const float* bo  = (const float*)d_in[10];
    float* out = (float*)d_out;

    dim3 grid(4096 / 4);   // 1024 waves = 1/SIMD
    dim3 block(64);        // 4 rows x 16 lanes, zero LDS
    gru_dpp3<<<grid, block, 0, stream>>>(x, W1, Ur1, b1, W2, Ur2, b2,
                                         Wd, bd, Wo, bo, out);
}